// Round 10
// baseline (208.228 us; speedup 1.0000x reference)
//
#include <hip/hip_runtime.h>

namespace {
constexpr int IMG_H = 376;
constexpr int IMG_W = 1248;
constexpr int HW = IMG_H * IMG_W;
constexpr int CV = 16;
constexpr int CR = 32;
constexpr int CO = CV + CR;   // 48
constexpr int K3 = 27;
constexpr int BLOCK = 256;    // 4 waves
constexpr int RPB = 128;      // rows per block (2 threads per row)
constexpr int LDSPAD = CO + 1; // 49 -> (17r + c) % 32, conflict-free
typedef float floatx4 __attribute__((ext_vector_type(4)));
typedef float floatx2 __attribute__((ext_vector_type(2)));
typedef floatx2 __attribute__((aligned(4))) floatx2u;   // dword-aligned 8B loads
}

// Per-batch precompute: Md = rect[s] @ Trv2c[s]; copy P2[s], prd[s].
// Layout per b (32 floats): [0:16) Md, [16:28) P2, [28] prd_u, [29] prd_v
__global__ void prep_kernel(const float* __restrict__ P2,
                            const float* __restrict__ Trv2c,
                            const float* __restrict__ rect,
                            const float* __restrict__ prd,
                            const int* __restrict__ dummy,
                            float* __restrict__ mats, int B) {
    int b = threadIdx.x;
    if (b >= B) return;
    int s = dummy[b];
    float* o = mats + b * 32;
    const float* R = rect + s * 16;
    const float* T = Trv2c + s * 16;
    for (int i = 0; i < 4; ++i) {
        for (int j = 0; j < 4; ++j) {
            float acc = R[i * 4 + 0] * T[0 * 4 + j];
            acc += R[i * 4 + 1] * T[1 * 4 + j];
            acc += R[i * 4 + 2] * T[2 * 4 + j];
            acc += R[i * 4 + 3] * T[3 * 4 + j];
            o[i * 4 + j] = acc;
        }
    }
    for (int i = 0; i < 12; ++i) o[16 + i] = P2[s * 12 + i];
    o[28] = prd[s * 2 + 0];
    o[29] = prd[s * 2 + 1];
}

__global__ __launch_bounds__(BLOCK, 8) void fuse_kernel(
        const float* __restrict__ vfeat,
        const float* __restrict__ rgb,
        const float* __restrict__ mats,
        const int* __restrict__ vcoords,
        float* __restrict__ out,
        int N) {
    const int M = N * K3;
    __shared__ float lds[4][16][LDSPAD];   // 12.5 KB

    const int t = threadIdx.x;
    const int wave = t >> 6;
    const int lane = t & 63;
    const int rl = lane >> 1;     // row-local 0..31
    const int h = lane & 1;       // channel-half
    const int waveRow0 = blockIdx.x * RPB + wave * 32;
    const int m = waveRow0 + rl;
    const bool inR = (m < M);

    // ---------- phase 1: geometry (per row, duplicated across the 2 h-threads)
    //            + 16-channel gather + this half's 8 vfeat floats ----------
    float s[CV];   // this thread's 16 rgb channels
    #pragma unroll
    for (int c = 0; c < CV; ++c) s[c] = 0.0f;
    floatx4 vfa = {0.f, 0.f, 0.f, 0.f}, vfb = {0.f, 0.f, 0.f, 0.f};

    if (inR) {
        int n = m / K3;
        int kk = m - n * K3;
        int4 vc = ((const int4*)vcoords)[n];
        int b = vc.x;
        int dz = kk / 9;
        int rem = kk - dz * 9;
        int dy = rem / 3;
        int dx = rem - dy * 3;

        // this half's 8 voxel-feature floats (vfeat row is 64B = 4 float4)
        const floatx4* vf4 = (const floatx4*)(vfeat + (size_t)n * CV);
        vfa = vf4[2 * h];
        vfb = vf4[2 * h + 1];

        float fz = ((float)(vc.y + dz - 1) + 0.5f) * 0.1f - 3.0f;
        float fy = ((float)(vc.z + dy - 1) + 0.5f) * 0.05f - 40.0f;
        float fx = ((float)(vc.w + dx - 1) + 0.5f) * 0.05f;

        const float* Mb = mats + b * 32;
        float cam0 = Mb[0]  * fx + Mb[1]  * fy + Mb[2]  * fz + Mb[3];
        float cam1 = Mb[4]  * fx + Mb[5]  * fy + Mb[6]  * fz + Mb[7];
        float cam2 = Mb[8]  * fx + Mb[9]  * fy + Mb[10] * fz + Mb[11];
        float cam3 = Mb[12] * fx + Mb[13] * fy + Mb[14] * fz + Mb[15];

        float img0 = Mb[16] * cam0 + Mb[17] * cam1 + Mb[18] * cam2 + Mb[19] * cam3;
        float img1 = Mb[20] * cam0 + Mb[21] * cam1 + Mb[22] * cam2 + Mb[23] * cam3;
        float img2 = Mb[24] * cam0 + Mb[25] * cam1 + Mb[26] * cam2 + Mb[27] * cam3;

        float depth = img2;
        float d = fmaxf(depth, 0.001f);
        float u = img0 / d + Mb[28];
        float v = img1 / d + Mb[29];

        bool valid = (depth > 0.001f) && (u >= 0.0f) && (u <= (float)(IMG_W - 1))
                     && (v >= 0.0f) && (v <= (float)(IMG_H - 1));

        if (valid) {
            // shift-clamp: identical math, guarantees x1=x0+1, y1=y0+1 in-bounds.
            int x0 = min((int)floorf(u), IMG_W - 2);
            int y0 = min((int)floorf(v), IMG_H - 2);
            float wx = u - (float)x0;
            float wy = v - (float)y0;
            float w00 = (1.0f - wx) * (1.0f - wy);
            float w10 = wx * (1.0f - wy);
            float w01 = (1.0f - wx) * wy;
            float w11 = wx * wy;
            const float* tap = rgb + (size_t)b * CR * HW
                             + (size_t)h * CV * HW      // this thread's channel half
                             + (size_t)y0 * IMG_W + x0;
            // 2 batches of 8 channels; per channel 2x 8B paired-tap loads.
            #pragma unroll
            for (int g2 = 0; g2 < 2; ++g2) {
                floatx2 r0[8], r1[8];
                #pragma unroll
                for (int c = 0; c < 8; ++c) {
                    const float* p = tap + (size_t)(g2 * 8 + c) * HW;
                    r0[c] = *(const floatx2u*)p;            // (y0,x0),(y0,x1)
                    r1[c] = *(const floatx2u*)(p + IMG_W);  // (y1,x0),(y1,x1)
                }
                __builtin_amdgcn_sched_group_barrier(0x020, 16, 0); // VMEM_READ x16
                #pragma unroll
                for (int c = 0; c < 8; ++c) {
                    s[g2 * 8 + c] = r0[c].x * w00 + r0[c].y * w10
                                  + r1[c].x * w01 + r1[c].y * w11;
                }
            }
        }
    }

    // ---------- phase 2: 2 chunks of 16 rows; reg -> LDS -> uniform coalesced NT stores ----------
    const size_t total = (size_t)M * CO;
    #pragma unroll 1
    for (int j = 0; j < 2; ++j) {
        __builtin_amdgcn_wave_barrier();
        if ((rl >> 4) == j && inR) {
            int r = rl & 15;
            // vfeat half -> cols [8h, 8h+8)
            *(floatx4*)&lds[wave][r][8 * h] = vfa;
            *(floatx4*)&lds[wave][r][8 * h + 4] = vfb;
            // rgb half -> cols [16 + 16h, 16 + 16h + 16)
            #pragma unroll
            for (int q = 0; q < 4; ++q) {
                *(floatx4*)&lds[wave][r][CV + CV * h + 4 * q] =
                    *(const floatx4*)&s[4 * q];
            }
        }
        __builtin_amdgcn_wave_barrier();
        // chunk rows [waveRow0 + 16j, +16) -> 768 floats contiguous
        size_t chunkBase = ((size_t)waveRow0 + (size_t)j * 16) * CO;
        #pragma unroll
        for (int i = 0; i < 3; ++i) {
            int g = i * 64 + lane;            // float4 index within chunk, 0..191
            int row = g / 12;                 // 16 rows * 12 float4s each
            int c4 = g - row * 12;            // 0..11
            int cc = c4 * 4;
            floatx4 val;
            val.x = lds[wave][row][cc + 0];
            val.y = lds[wave][row][cc + 1];
            val.z = lds[wave][row][cc + 2];
            val.w = lds[wave][row][cc + 3];
            size_t idx = chunkBase + (size_t)g * 4;
            if (idx < total) {
                // non-temporal: keep the 202 MB write stream from evicting rgb in L2
                __builtin_nontemporal_store(val, (floatx4*)(out + idx));
            }
        }
        __builtin_amdgcn_wave_barrier();
    }
}

extern "C" void kernel_launch(void* const* d_in, const int* in_sizes, int n_in,
                              void* d_out, int out_size, void* d_ws, size_t ws_size,
                              hipStream_t stream) {
    const float* vfeat  = (const float*)d_in[0];
    const float* rgb    = (const float*)d_in[1];
    const float* P2     = (const float*)d_in[2];
    const float* Trv2c  = (const float*)d_in[3];
    const float* rect   = (const float*)d_in[4];
    const float* prd    = (const float*)d_in[5];
    const int* vcoords  = (const int*)d_in[6];
    const int* dummy    = (const int*)d_in[7];
    float* out = (float*)d_out;

    int B = in_sizes[7];
    int N = in_sizes[6] / 4;
    float* mats = (float*)d_ws;   // B * 32 floats

    prep_kernel<<<1, 64, 0, stream>>>(P2, Trv2c, rect, prd, dummy, mats, B);

    int M = N * K3;
    int blocks = (M + RPB - 1) / RPB;
    fuse_kernel<<<blocks, BLOCK, 0, stream>>>(vfeat, rgb, mats, vcoords, out, N);
}

// Round 11
// 192.753 us; speedup vs baseline: 1.0803x; 1.0803x over previous
//
#include <hip/hip_runtime.h>

namespace {
constexpr int IMG_H = 376;
constexpr int IMG_W = 1248;
constexpr int HW = IMG_H * IMG_W;
constexpr int CV = 16;
constexpr int CR = 32;
constexpr int CO = CV + CR;   // 48
constexpr int K3 = 27;
constexpr int BLOCK = 256;    // 4 waves
constexpr int RPB = 128;      // rows per block (2 threads per row)
constexpr int LDSPAD = 56;    // 224B rows: 16B-aligned so ds_read/write are b128
typedef float floatx4 __attribute__((ext_vector_type(4)));
typedef float floatx2 __attribute__((ext_vector_type(2)));
typedef floatx2 __attribute__((aligned(4))) floatx2u;   // dword-aligned 8B loads
}

// Per-batch precompute: Md = rect[s] @ Trv2c[s]; copy P2[s], prd[s].
// Layout per b (32 floats): [0:16) Md, [16:28) P2, [28] prd_u, [29] prd_v
__global__ void prep_kernel(const float* __restrict__ P2,
                            const float* __restrict__ Trv2c,
                            const float* __restrict__ rect,
                            const float* __restrict__ prd,
                            const int* __restrict__ dummy,
                            float* __restrict__ mats, int B) {
    int b = threadIdx.x;
    if (b >= B) return;
    int s = dummy[b];
    float* o = mats + b * 32;
    const float* R = rect + s * 16;
    const float* T = Trv2c + s * 16;
    for (int i = 0; i < 4; ++i) {
        for (int j = 0; j < 4; ++j) {
            float acc = R[i * 4 + 0] * T[0 * 4 + j];
            acc += R[i * 4 + 1] * T[1 * 4 + j];
            acc += R[i * 4 + 2] * T[2 * 4 + j];
            acc += R[i * 4 + 3] * T[3 * 4 + j];
            o[i * 4 + j] = acc;
        }
    }
    for (int i = 0; i < 12; ++i) o[16 + i] = P2[s * 12 + i];
    o[28] = prd[s * 2 + 0];
    o[29] = prd[s * 2 + 1];
}

__global__ __launch_bounds__(BLOCK, 8) void fuse_kernel(
        const float* __restrict__ vfeat,
        const float* __restrict__ rgb,
        const float* __restrict__ mats,
        const int* __restrict__ vcoords,
        float* __restrict__ out,
        int N) {
    const int M = N * K3;
    __shared__ float lds[4][16][LDSPAD];   // 14 KB

    const int t = threadIdx.x;
    const int wave = t >> 6;
    const int lane = t & 63;
    const int rl = lane >> 1;     // row-local 0..31
    const int h = lane & 1;       // channel-half
    const int waveRow0 = blockIdx.x * RPB + wave * 32;
    const int m = waveRow0 + rl;
    const bool inR = (m < M);

    // ---------- phase 1: geometry (per row, duplicated across the 2 h-threads)
    //            + 16-channel gather + this half's 8 vfeat floats ----------
    float s[CV];   // this thread's 16 rgb channels
    #pragma unroll
    for (int c = 0; c < CV; ++c) s[c] = 0.0f;
    floatx4 vfa = {0.f, 0.f, 0.f, 0.f}, vfb = {0.f, 0.f, 0.f, 0.f};

    if (inR) {
        int n = m / K3;
        int kk = m - n * K3;
        int4 vc = ((const int4*)vcoords)[n];
        int b = vc.x;
        int dz = kk / 9;
        int rem = kk - dz * 9;
        int dy = rem / 3;
        int dx = rem - dy * 3;

        // this half's 8 voxel-feature floats (vfeat row is 64B = 4 float4)
        const floatx4* vf4 = (const floatx4*)(vfeat + (size_t)n * CV);
        vfa = vf4[2 * h];
        vfb = vf4[2 * h + 1];

        float fz = ((float)(vc.y + dz - 1) + 0.5f) * 0.1f - 3.0f;
        float fy = ((float)(vc.z + dy - 1) + 0.5f) * 0.05f - 40.0f;
        float fx = ((float)(vc.w + dx - 1) + 0.5f) * 0.05f;

        const float* Mb = mats + b * 32;
        float cam0 = Mb[0]  * fx + Mb[1]  * fy + Mb[2]  * fz + Mb[3];
        float cam1 = Mb[4]  * fx + Mb[5]  * fy + Mb[6]  * fz + Mb[7];
        float cam2 = Mb[8]  * fx + Mb[9]  * fy + Mb[10] * fz + Mb[11];
        float cam3 = Mb[12] * fx + Mb[13] * fy + Mb[14] * fz + Mb[15];

        float img0 = Mb[16] * cam0 + Mb[17] * cam1 + Mb[18] * cam2 + Mb[19] * cam3;
        float img1 = Mb[20] * cam0 + Mb[21] * cam1 + Mb[22] * cam2 + Mb[23] * cam3;
        float img2 = Mb[24] * cam0 + Mb[25] * cam1 + Mb[26] * cam2 + Mb[27] * cam3;

        float depth = img2;
        float d = fmaxf(depth, 0.001f);
        float u = img0 / d + Mb[28];
        float v = img1 / d + Mb[29];

        bool valid = (depth > 0.001f) && (u >= 0.0f) && (u <= (float)(IMG_W - 1))
                     && (v >= 0.0f) && (v <= (float)(IMG_H - 1));

        if (valid) {
            // shift-clamp: identical math, guarantees x1=x0+1, y1=y0+1 in-bounds.
            int x0 = min((int)floorf(u), IMG_W - 2);
            int y0 = min((int)floorf(v), IMG_H - 2);
            float wx = u - (float)x0;
            float wy = v - (float)y0;
            float w00 = (1.0f - wx) * (1.0f - wy);
            float w10 = wx * (1.0f - wy);
            float w01 = (1.0f - wx) * wy;
            float w11 = wx * wy;
            const float* tap = rgb + (size_t)b * CR * HW
                             + (size_t)h * CV * HW      // this thread's channel half
                             + (size_t)y0 * IMG_W + x0;
            // 2 batches of 8 channels; per channel 2x 8B paired-tap loads.
            #pragma unroll
            for (int g2 = 0; g2 < 2; ++g2) {
                floatx2 r0[8], r1[8];
                #pragma unroll
                for (int c = 0; c < 8; ++c) {
                    const float* p = tap + (size_t)(g2 * 8 + c) * HW;
                    r0[c] = *(const floatx2u*)p;            // (y0,x0),(y0,x1)
                    r1[c] = *(const floatx2u*)(p + IMG_W);  // (y1,x0),(y1,x1)
                }
                __builtin_amdgcn_sched_group_barrier(0x020, 16, 0); // VMEM_READ x16
                #pragma unroll
                for (int c = 0; c < 8; ++c) {
                    s[g2 * 8 + c] = r0[c].x * w00 + r0[c].y * w10
                                  + r1[c].x * w01 + r1[c].y * w11;
                }
            }
        }
    }

    // ---------- phase 2: 2 chunks of 16 rows; reg -> LDS (b128) -> uniform dwordx4 NT stores ----------
    const size_t total = (size_t)M * CO;
    #pragma unroll 1
    for (int j = 0; j < 2; ++j) {
        __builtin_amdgcn_wave_barrier();
        if ((rl >> 4) == j && inR) {
            int r = rl & 15;
            // vfeat half -> cols [8h, 8h+8)   (all 16B-aligned: row stride 224B)
            *(floatx4*)&lds[wave][r][8 * h] = vfa;
            *(floatx4*)&lds[wave][r][8 * h + 4] = vfb;
            // rgb half -> cols [16 + 16h, 16 + 16h + 16)
            #pragma unroll
            for (int q = 0; q < 4; ++q) {
                *(floatx4*)&lds[wave][r][CV + CV * h + 4 * q] =
                    *(const floatx4*)&s[4 * q];
            }
        }
        __builtin_amdgcn_wave_barrier();
        // chunk rows [waveRow0 + 16j, +16) -> 768 floats contiguous
        size_t chunkBase = ((size_t)waveRow0 + (size_t)j * 16) * CO;
        #pragma unroll
        for (int i = 0; i < 3; ++i) {
            int g = i * 64 + lane;            // float4 index within chunk, 0..191
            int row = g / 12;                 // 16 rows * 12 float4s each
            int c4 = g - row * 12;            // 0..11
            floatx4 val = *(const floatx4*)&lds[wave][row][c4 * 4];  // b128 read
            size_t idx = chunkBase + (size_t)g * 4;
            if (idx < total) {
                // full-mask dwordx4 NT store: 1024B contiguous per instruction
                __builtin_nontemporal_store(val, (floatx4*)(out + idx));
            }
        }
        __builtin_amdgcn_wave_barrier();
    }
}

extern "C" void kernel_launch(void* const* d_in, const int* in_sizes, int n_in,
                              void* d_out, int out_size, void* d_ws, size_t ws_size,
                              hipStream_t stream) {
    const float* vfeat  = (const float*)d_in[0];
    const float* rgb    = (const float*)d_in[1];
    const float* P2     = (const float*)d_in[2];
    const float* Trv2c  = (const float*)d_in[3];
    const float* rect   = (const float*)d_in[4];
    const float* prd    = (const float*)d_in[5];
    const int* vcoords  = (const int*)d_in[6];
    const int* dummy    = (const int*)d_in[7];
    float* out = (float*)d_out;

    int B = in_sizes[7];
    int N = in_sizes[6] / 4;
    float* mats = (float*)d_ws;   // B * 32 floats

    prep_kernel<<<1, 64, 0, stream>>>(P2, Trv2c, rect, prd, dummy, mats, B);

    int M = N * K3;
    int blocks = (M + RPB - 1) / RPB;
    fuse_kernel<<<blocks, BLOCK, 0, stream>>>(vfeat, rgb, mats, vcoords, out, N);
}

// Round 12
// 134.401 us; speedup vs baseline: 1.5493x; 1.4342x over previous
//
#include <hip/hip_runtime.h>

namespace {
constexpr int IMG_H = 376;
constexpr int IMG_W = 1248;
constexpr int HW = IMG_H * IMG_W;
constexpr int CV = 16;
constexpr int CR = 32;
constexpr int CO = CV + CR;   // 48
constexpr int K3 = 27;
constexpr int BLOCK = 256;    // 4 waves; each wave owns 64 rows
constexpr int LDSPAD = 56;    // 224B rows: 16B-aligned -> b128 ds ops, clean stores
typedef float floatx4 __attribute__((ext_vector_type(4)));
typedef float floatx2 __attribute__((ext_vector_type(2)));
typedef floatx2 __attribute__((aligned(4))) floatx2u;   // dword-aligned 8B loads
}

// Per-batch precompute: Md = rect[s] @ Trv2c[s]; copy P2[s], prd[s].
// Layout per b (32 floats): [0:16) Md, [16:28) P2, [28] prd_u, [29] prd_v
__global__ void prep_kernel(const float* __restrict__ P2,
                            const float* __restrict__ Trv2c,
                            const float* __restrict__ rect,
                            const float* __restrict__ prd,
                            const int* __restrict__ dummy,
                            float* __restrict__ mats, int B) {
    int b = threadIdx.x;
    if (b >= B) return;
    int s = dummy[b];
    float* o = mats + b * 32;
    const float* R = rect + s * 16;
    const float* T = Trv2c + s * 16;
    for (int i = 0; i < 4; ++i) {
        for (int j = 0; j < 4; ++j) {
            float acc = R[i * 4 + 0] * T[0 * 4 + j];
            acc += R[i * 4 + 1] * T[1 * 4 + j];
            acc += R[i * 4 + 2] * T[2 * 4 + j];
            acc += R[i * 4 + 3] * T[3 * 4 + j];
            o[i * 4 + j] = acc;
        }
    }
    for (int i = 0; i < 12; ++i) o[16 + i] = P2[s * 12 + i];
    o[28] = prd[s * 2 + 0];
    o[29] = prd[s * 2 + 1];
}

__global__ __launch_bounds__(BLOCK, 4) void fuse_kernel(
        const float* __restrict__ vfeat,
        const float* __restrict__ rgb,
        const float* __restrict__ mats,
        const int* __restrict__ vcoords,
        float* __restrict__ out,
        int N) {
    const int M = N * K3;
    __shared__ float lds[4][16][LDSPAD];   // 14 KB total

    const int t = threadIdx.x;
    const int wave = t >> 6;
    const int lane = t & 63;
    const int waveBase = blockIdx.x * BLOCK + wave * 64;
    const int m = waveBase + lane;
    const bool inR = (m < M);

    // ---------- phase 1: thread-per-row geometry + gather into registers ----------
    float s[CO];
    #pragma unroll
    for (int c = 0; c < CO; ++c) s[c] = 0.0f;

    if (inR) {
        int n = m / K3;
        int kk = m - n * K3;
        int4 vc = ((const int4*)vcoords)[n];
        int b = vc.x;
        int dz = kk / 9;
        int rem = kk - dz * 9;
        int dy = rem / 3;
        int dx = rem - dy * 3;

        float fz = ((float)(vc.y + dz - 1) + 0.5f) * 0.1f - 3.0f;
        float fy = ((float)(vc.z + dy - 1) + 0.5f) * 0.05f - 40.0f;
        float fx = ((float)(vc.w + dx - 1) + 0.5f) * 0.05f;

        const float* Mb = mats + b * 32;
        float cam0 = Mb[0]  * fx + Mb[1]  * fy + Mb[2]  * fz + Mb[3];
        float cam1 = Mb[4]  * fx + Mb[5]  * fy + Mb[6]  * fz + Mb[7];
        float cam2 = Mb[8]  * fx + Mb[9]  * fy + Mb[10] * fz + Mb[11];
        float cam3 = Mb[12] * fx + Mb[13] * fy + Mb[14] * fz + Mb[15];

        float img0 = Mb[16] * cam0 + Mb[17] * cam1 + Mb[18] * cam2 + Mb[19] * cam3;
        float img1 = Mb[20] * cam0 + Mb[21] * cam1 + Mb[22] * cam2 + Mb[23] * cam3;
        float img2 = Mb[24] * cam0 + Mb[25] * cam1 + Mb[26] * cam2 + Mb[27] * cam3;

        float depth = img2;
        float d = fmaxf(depth, 0.001f);
        float u = img0 / d + Mb[28];
        float v = img1 / d + Mb[29];

        bool valid = (depth > 0.001f) && (u >= 0.0f) && (u <= (float)(IMG_W - 1))
                     && (v >= 0.0f) && (v <= (float)(IMG_H - 1));

        // voxel features (scalar assigns keep s[] in registers)
        const float4* vp4 = (const float4*)(vfeat + (size_t)n * CV);
        float4 vf0 = vp4[0], vf1 = vp4[1], vf2 = vp4[2], vf3 = vp4[3];
        s[0] = vf0.x;  s[1] = vf0.y;  s[2]  = vf0.z;  s[3]  = vf0.w;
        s[4] = vf1.x;  s[5] = vf1.y;  s[6]  = vf1.z;  s[7]  = vf1.w;
        s[8] = vf2.x;  s[9] = vf2.y;  s[10] = vf2.z;  s[11] = vf2.w;
        s[12] = vf3.x; s[13] = vf3.y; s[14] = vf3.z;  s[15] = vf3.w;

        if (valid) {
            // shift-clamp: identical math, guarantees x1=x0+1, y1=y0+1 in-bounds.
            int x0 = min((int)floorf(u), IMG_W - 2);
            int y0 = min((int)floorf(v), IMG_H - 2);
            float wx = u - (float)x0;
            float wy = v - (float)y0;
            float w00 = (1.0f - wx) * (1.0f - wy);
            float w10 = wx * (1.0f - wy);
            float w01 = (1.0f - wx) * wy;
            float w11 = wx * wy;
            const float* tap = rgb + (size_t)b * CR * HW + (size_t)y0 * IMG_W + x0;

            // Issue ALL 64 paired-tap loads before any FMA: max per-wave MLP.
            floatx2 r0[CR], r1[CR];
            #pragma unroll
            for (int c = 0; c < CR; ++c) {
                const float* p = tap + (size_t)c * HW;
                r0[c] = *(const floatx2u*)p;            // (y0,x0),(y0,x1)
                r1[c] = *(const floatx2u*)(p + IMG_W);  // (y1,x0),(y1,x1)
            }
            __builtin_amdgcn_sched_group_barrier(0x020, 64, 0); // VMEM_READ x64 first
            #pragma unroll
            for (int c = 0; c < CR; ++c) {
                s[CV + c] = r0[c].x * w00 + r0[c].y * w10
                          + r1[c].x * w01 + r1[c].y * w11;
            }
        }
    }

    // ---------- phase 2: 4 chunks of 16 rows; reg -> LDS (b128) -> dwordx4 NT stores ----------
    const size_t total = (size_t)M * CO;
    #pragma unroll 1
    for (int j = 0; j < 4; ++j) {
        __builtin_amdgcn_wave_barrier();
        if ((lane >> 4) == j && inR) {
            int r = lane & 15;
            #pragma unroll
            for (int q = 0; q < CO / 4; ++q) {
                *(floatx4*)&lds[wave][r][4 * q] = *(const floatx4*)&s[4 * q];
            }
        }
        __builtin_amdgcn_wave_barrier();
        // chunk output region: rows [waveBase + 16j, +16) -> 768 floats contiguous
        size_t chunkBase = ((size_t)waveBase + (size_t)j * 16) * CO;
        #pragma unroll
        for (int i = 0; i < 3; ++i) {
            int g = i * 64 + lane;            // float4 index within chunk, 0..191
            int row = g / 12;                 // 16 rows * 12 float4s each
            int c4 = g - row * 12;            // 0..11
            floatx4 val = *(const floatx4*)&lds[wave][row][c4 * 4];  // b128 read
            size_t idx = chunkBase + (size_t)g * 4;
            if (idx < total) {
                // full-mask dwordx4 NT store: 1024B contiguous per instruction
                __builtin_nontemporal_store(val, (floatx4*)(out + idx));
            }
        }
        __builtin_amdgcn_wave_barrier();
    }
}

extern "C" void kernel_launch(void* const* d_in, const int* in_sizes, int n_in,
                              void* d_out, int out_size, void* d_ws, size_t ws_size,
                              hipStream_t stream) {
    const float* vfeat  = (const float*)d_in[0];
    const float* rgb    = (const float*)d_in[1];
    const float* P2     = (const float*)d_in[2];
    const float* Trv2c  = (const float*)d_in[3];
    const float* rect   = (const float*)d_in[4];
    const float* prd    = (const float*)d_in[5];
    const int* vcoords  = (const int*)d_in[6];
    const int* dummy    = (const int*)d_in[7];
    float* out = (float*)d_out;

    int B = in_sizes[7];
    int N = in_sizes[6] / 4;
    float* mats = (float*)d_ws;   // B * 32 floats

    prep_kernel<<<1, 64, 0, stream>>>(P2, Trv2c, rect, prd, dummy, mats, B);

    int M = N * K3;
    int blocks = (M + BLOCK - 1) / BLOCK;
    fuse_kernel<<<blocks, BLOCK, 0, stream>>>(vfeat, rgb, mats, vcoords, out, N);
}